// Round 1
// 3546.267 us; speedup vs baseline: 2.3095x; 2.3095x over previous
//
#include <hip/hip_runtime.h>
#include <math.h>

typedef _Float16 f16;
typedef __attribute__((ext_vector_type(4))) _Float16 f16x4;
typedef __attribute__((ext_vector_type(8))) _Float16 f16x8;
typedef __attribute__((ext_vector_type(4))) float f32x4;

#define LDSD 40   // LDS row stride in halves (80 B) -> <=2-way bank aliasing (free)

// ---------------- embedding + positional encoding ----------------
__global__ __launch_bounds__(256) void embed_kernel(const int* __restrict__ toks,
    const float* __restrict__ emb, float* __restrict__ X)
{
    int row = blockIdx.x;
    int s   = row & 511;
    int tok = toks[row];
    const float* e = emb + (long)tok * 512;
    float* x = X + (long)row * 512;
    int j = threadIdx.x;
#pragma unroll
    for (int u = 0; u < 2; u++, j += 256) {
        int i = j >> 1;
        float freq = expf((float)(2 * i) * (-9.210340371976184f / 512.0f));
        float ang  = (float)s * freq;
        float pe   = (j & 1) ? cosf(ang) : sinf(ang);
        x[j] = e[j] * 22.62741699796952f + pe;  // sqrt(512)
    }
}

// ---------------- layernorm over D=512, one block per row ----------------
__global__ __launch_bounds__(256) void ln_kernel(const float* __restrict__ X,
    float* __restrict__ Y, const float* __restrict__ g, const float* __restrict__ b)
{
    long row = blockIdx.x;
    const float* x = X + row * 512;
    float* y = Y + row * 512;
    int tid = threadIdx.x;
    float v0 = x[tid], v1 = x[tid + 256];
    float s = v0 + v1;
#pragma unroll
    for (int o = 32; o; o >>= 1) s += __shfl_xor(s, o);
    __shared__ float red[8];
    int w = tid >> 6;
    if ((tid & 63) == 0) red[w] = s;
    __syncthreads();
    float mean = (red[0] + red[1] + red[2] + red[3]) * (1.0f / 512.0f);
    float d0 = v0 - mean, d1 = v1 - mean;
    float t = d0 * d0 + d1 * d1;
#pragma unroll
    for (int o = 32; o; o >>= 1) t += __shfl_xor(t, o);
    if ((tid & 63) == 0) red[4 + w] = t;
    __syncthreads();
    float var = (red[4] + red[5] + red[6] + red[7]) * (1.0f / 512.0f);
    float rs = rsqrtf(var + 1e-5f);
    y[tid]       = d0 * rs * g[tid]       + b[tid];
    y[tid + 256] = d1 * rs * g[tid + 256] + b[tid + 256];
}

// ---------------- masked softmax over rows of 512 (in-place on scores) ----
__global__ __launch_bounds__(256) void softmax_kernel(float* __restrict__ SC,
    const int* __restrict__ toks, int causal, float scale)
{
    int q = blockIdx.x, z = blockIdx.y;
    int b = z >> 3;                       // H = 8
    float* row = SC + ((long)z * 512 + q) * 512;
    const int* tk = toks + b * 512;
    int tid = threadIdx.x;
    int c0 = tid, c1 = tid + 256;
    bool m0 = (tk[c0] != 0) && (!causal || c0 <= q);
    bool m1 = (tk[c1] != 0) && (!causal || c1 <= q);
    float v0 = m0 ? row[c0] * scale : -1e9f;
    float v1 = m1 ? row[c1] * scale : -1e9f;
    float mx = fmaxf(v0, v1);
#pragma unroll
    for (int o = 32; o; o >>= 1) mx = fmaxf(mx, __shfl_xor(mx, o));
    __shared__ float red[8];
    int w = tid >> 6;
    if ((tid & 63) == 0) red[w] = mx;
    __syncthreads();
    mx = fmaxf(fmaxf(red[0], red[1]), fmaxf(red[2], red[3]));
    float p0 = __expf(v0 - mx), p1 = __expf(v1 - mx);
    float s = p0 + p1;
#pragma unroll
    for (int o = 32; o; o >>= 1) s += __shfl_xor(s, o);
    if ((tid & 63) == 0) red[4 + w] = s;
    __syncthreads();
    float inv = 1.0f / (red[4] + red[5] + red[6] + red[7]);
    row[c0] = p0 * inv;
    row[c1] = p1 * inv;
}

// ---------------- MFMA fp16 tiled GEMM (fp32 in/out, fp32 accumulate) -----
// C[M,N] = act( A[M,K] * op(B) + bias + resid )
//   NT=true : op(B)=B^T, B is [N,K] row-major (nn.Linear layout / QK^T)
//   NT=false: op(B)=B,   B is [K,N] row-major (P*V)
// Block = 64x64 tile, 4 waves, each wave owns 32x32 via 2x2 mfma_f32_16x16x32_f16.
// Inputs converted fp32->fp16 at staging; accumulate fp32 (error ~2^-11 per product).
// Requires M,N multiples of 64 and K multiple of 32 (true for all call sites).
template<bool NT, bool RELU, bool RESID, bool BIAS>
__global__ __launch_bounds__(256) void gemm_kernel(
    const float* __restrict__ A, const float* __restrict__ B,
    const float* __restrict__ bias, const float* __restrict__ resid,
    float* __restrict__ C, int M, int N, int K,
    int lda, int ldb, int ldc,
    int nh, long sAb, long sAh, long sBb, long sBh, long sCb, long sCh)
{
    int z = blockIdx.z;
    int zb = z / nh, zh = z % nh;
    A += (long)zb * sAb + (long)zh * sAh;
    B += (long)zb * sBb + (long)zh * sBh;
    C += (long)zb * sCb + (long)zh * sCh;

    __shared__ f16 As[64 * LDSD];   // [row m][k], padded
    __shared__ f16 Bs[64 * LDSD];   // [col n][k], padded (always k-contiguous)

    const int t  = threadIdx.x;
    const int bm = blockIdx.y * 64, bn = blockIdx.x * 64;

    const int lane = t & 63;
    const int wid  = t >> 6;
    const int wr = (wid >> 1) * 32;   // wave row origin in tile
    const int wc = (wid & 1)  * 32;   // wave col origin in tile
    const int fr = lane & 15;         // fragment row/col index
    const int kq = lane >> 4;         // k-octet selector (A/B frag: k = kq*8+j)

    // staging indices: NT path loads float4 along k (fully coalesced rows)
    const int sr = t >> 3;            // 0..31
    const int sc = (t & 7) * 4;       // 0,4,..,28 (floats within 32-wide k-step)
    // NN path (B=[K,N]): thread owns one n, 8 consecutive k
    const int bnn = t & 63, bkg = t >> 6;

    f32x4 acc[2][2] = {};

    for (int k0 = 0; k0 < K; k0 += 32) {
        // ---- issue global loads (in flight across the barrier) ----
        float4 a0 = *(const float4*)&A[(long)(bm + sr)      * lda + (k0 + sc)];
        float4 a1 = *(const float4*)&A[(long)(bm + sr + 32) * lda + (k0 + sc)];
        float4 b0, b1;
        float  bv[8];
        if constexpr (NT) {
            b0 = *(const float4*)&B[(long)(bn + sr)      * ldb + (k0 + sc)];
            b1 = *(const float4*)&B[(long)(bn + sr + 32) * ldb + (k0 + sc)];
        } else {
#pragma unroll
            for (int j = 0; j < 8; j++)
                bv[j] = B[(long)(k0 + bkg * 8 + j) * ldb + (bn + bnn)];
        }

        __syncthreads();   // previous iteration's fragment reads complete

        *(f16x4*)&As[sr * LDSD + sc] =
            f16x4{(f16)a0.x, (f16)a0.y, (f16)a0.z, (f16)a0.w};
        *(f16x4*)&As[(sr + 32) * LDSD + sc] =
            f16x4{(f16)a1.x, (f16)a1.y, (f16)a1.z, (f16)a1.w};
        if constexpr (NT) {
            *(f16x4*)&Bs[sr * LDSD + sc] =
                f16x4{(f16)b0.x, (f16)b0.y, (f16)b0.z, (f16)b0.w};
            *(f16x4*)&Bs[(sr + 32) * LDSD + sc] =
                f16x4{(f16)b1.x, (f16)b1.y, (f16)b1.z, (f16)b1.w};
        } else {
            f16x8 h;
#pragma unroll
            for (int j = 0; j < 8; j++) h[j] = (f16)bv[j];
            *(f16x8*)&Bs[bnn * LDSD + bkg * 8] = h;
        }

        __syncthreads();   // tile visible

        // ---- fragments: A[m][k]: m=fr, k=kq*8+j ; B[k][n]: n=fr, k=kq*8+j ----
        f16x8 af0 = *(const f16x8*)&As[(wr +      fr) * LDSD + kq * 8];
        f16x8 af1 = *(const f16x8*)&As[(wr + 16 + fr) * LDSD + kq * 8];
        f16x8 bf0 = *(const f16x8*)&Bs[(wc +      fr) * LDSD + kq * 8];
        f16x8 bf1 = *(const f16x8*)&Bs[(wc + 16 + fr) * LDSD + kq * 8];

        acc[0][0] = __builtin_amdgcn_mfma_f32_16x16x32_f16(af0, bf0, acc[0][0], 0, 0, 0);
        acc[0][1] = __builtin_amdgcn_mfma_f32_16x16x32_f16(af0, bf1, acc[0][1], 0, 0, 0);
        acc[1][0] = __builtin_amdgcn_mfma_f32_16x16x32_f16(af1, bf0, acc[1][0], 0, 0, 0);
        acc[1][1] = __builtin_amdgcn_mfma_f32_16x16x32_f16(af1, bf1, acc[1][1], 0, 0, 0);
    }

    // ---- epilogue: C/D layout col=lane&15, row=(lane>>4)*4+reg ----
#pragma unroll
    for (int i = 0; i < 2; i++) {
#pragma unroll
        for (int r = 0; r < 4; r++) {
            int  row  = bm + wr + i * 16 + kq * 4 + r;
            long base = (long)row * ldc + bn;
#pragma unroll
            for (int j = 0; j < 2; j++) {
                int col = wc + j * 16 + fr;
                float v = acc[i][j][r];
                if (BIAS)  v += bias[bn + col];
                if (RESID) v += resid[base + col];
                if (RELU)  v = fmaxf(v, 0.0f);
                C[base + col] = v;
            }
        }
    }
    (void)M; (void)N;
}

// =======================================================================
extern "C" void kernel_launch(void* const* d_in, const int* in_sizes, int n_in,
                              void* d_out, int out_size, void* d_ws, size_t ws_size,
                              hipStream_t stream)
{
    const int*   src = (const int*)d_in[0];
    const int*   tgt = (const int*)d_in[1];
    const float* emb = (const float*)d_in[2];
    const float* eaw = (const float*)d_in[3];
    const float* eab = (const float*)d_in[4];
    const float* elg = (const float*)d_in[5];
    const float* elb = (const float*)d_in[6];
    const float* ew1 = (const float*)d_in[7];
    const float* eb1 = (const float*)d_in[8];
    const float* ew2 = (const float*)d_in[9];
    const float* eb2 = (const float*)d_in[10];
    const float* daw = (const float*)d_in[11];
    const float* dab = (const float*)d_in[12];
    const float* dlg = (const float*)d_in[13];
    const float* dlb = (const float*)d_in[14];
    const float* dw1 = (const float*)d_in[15];
    const float* db1 = (const float*)d_in[16];
    const float* dw2 = (const float*)d_in[17];
    const float* db2 = (const float*)d_in[18];
    const float* eng = (const float*)d_in[19];
    const float* enb = (const float*)d_in[20];
    const float* dng = (const float*)d_in[21];
    const float* dnb = (const float*)d_in[22];

    // workspace layout (floats): ~120 MB total
    float* X   = (float*)d_ws;        // [4096, 512]   activations
    float* X2  = X   + 2097152;       // [4096, 512]   layernorm out
    float* QKV = X2  + 2097152;       // [4096, 1536]  q|k|v concat
    float* CTX = QKV + 6291456;       // [4096, 512]   attention context
    float* ENC = CTX + 2097152;       // [4096, 512]   encoder output
    float* SC  = ENC + 2097152;       // [64, 512, 512] scores / probs
    float* FH  = SC;                  // [4096, 2048]  ffn hidden (overlaps SC)

    const long DD = 262144;           // 512*512
    dim3 blk(256);

    auto attn = [&](const int* mtoks, int causal) {
        // scores[z=b*8+h][q][kv] = Q . K  (raw; scale+mask in softmax)
        gemm_kernel<true,false,false,false><<<dim3(8,8,64),blk,0,stream>>>(
            QKV, QKV + 512, nullptr, nullptr, SC, 512,512,64, 1536,1536,512,
            8, 786432L,64L, 786432L,64L, 2097152L,262144L);
        softmax_kernel<<<dim3(512,64),blk,0,stream>>>(SC, mtoks, causal, 0.125f);
        // ctx = P * V
        gemm_kernel<false,false,false,false><<<dim3(1,8,64),blk,0,stream>>>(
            SC, QKV + 1024, nullptr, nullptr, CTX, 512,64,512, 512,1536,512,
            8, 2097152L,262144L, 786432L,64L, 262144L,64L);
    };

    // ===================== encoder =====================
    embed_kernel<<<4096,blk,0,stream>>>(src, emb, X);
    for (int l = 0; l < 4; l++) {
        const float* w  = eaw + (long)l * 4 * DD;
        const float* bb = eab + l * 4 * 512;
        ln_kernel<<<4096,blk,0,stream>>>(X, X2, elg + (l*2+0)*512, elb + (l*2+0)*512);
        gemm_kernel<true,false,false,true><<<dim3(24,64,1),blk,0,stream>>>(
            X2, w, bb, nullptr, QKV, 4096,1536,512, 512,512,1536, 1,0,0,0,0,0,0);
        attn(src, 0);
        gemm_kernel<true,false,true,true><<<dim3(8,64,1),blk,0,stream>>>(
            CTX, w + 3*DD, bb + 3*512, X, X, 4096,512,512, 512,512,512, 1,0,0,0,0,0,0);
        ln_kernel<<<4096,blk,0,stream>>>(X, X2, elg + (l*2+1)*512, elb + (l*2+1)*512);
        gemm_kernel<true,true,false,true><<<dim3(32,64,1),blk,0,stream>>>(
            X2, ew1 + (long)l*2048*512, eb1 + l*2048, nullptr, FH,
            4096,2048,512, 512,512,2048, 1,0,0,0,0,0,0);
        gemm_kernel<true,false,true,true><<<dim3(8,64,1),blk,0,stream>>>(
            FH, ew2 + (long)l*512*2048, eb2 + l*512, X, X,
            4096,512,2048, 2048,2048,512, 1,0,0,0,0,0,0);
    }
    ln_kernel<<<4096,blk,0,stream>>>(X, ENC, eng, enb);

    // ===================== decoder =====================
    embed_kernel<<<4096,blk,0,stream>>>(tgt, emb, X);
    for (int l = 0; l < 4; l++) {
        const float* w  = daw + (long)l * 8 * DD;
        const float* bb = dab + l * 8 * 512;
        // self-attention (causal + tgt padding mask)
        ln_kernel<<<4096,blk,0,stream>>>(X, X2, dlg + (l*3+0)*512, dlb + (l*3+0)*512);
        gemm_kernel<true,false,false,true><<<dim3(24,64,1),blk,0,stream>>>(
            X2, w, bb, nullptr, QKV, 4096,1536,512, 512,512,1536, 1,0,0,0,0,0,0);
        attn(tgt, 1);
        gemm_kernel<true,false,true,true><<<dim3(8,64,1),blk,0,stream>>>(
            CTX, w + 3*DD, bb + 3*512, X, X, 4096,512,512, 512,512,512, 1,0,0,0,0,0,0);
        // cross-attention (src padding mask), K/V from encoder output
        ln_kernel<<<4096,blk,0,stream>>>(X, X2, dlg + (l*3+1)*512, dlb + (l*3+1)*512);
        gemm_kernel<true,false,false,true><<<dim3(8,64,1),blk,0,stream>>>(
            X2, w + 4*DD, bb + 4*512, nullptr, QKV, 4096,512,512, 512,512,1536, 1,0,0,0,0,0,0);
        gemm_kernel<true,false,false,true><<<dim3(16,64,1),blk,0,stream>>>(
            ENC, w + 5*DD, bb + 5*512, nullptr, QKV + 512, 4096,1024,512, 512,512,1536, 1,0,0,0,0,0,0);
        attn(src, 0);
        gemm_kernel<true,false,true,true><<<dim3(8,64,1),blk,0,stream>>>(
            CTX, w + 7*DD, bb + 7*512, X, X, 4096,512,512, 512,512,512, 1,0,0,0,0,0,0);
        // ffn
        ln_kernel<<<4096,blk,0,stream>>>(X, X2, dlg + (l*3+2)*512, dlb + (l*3+2)*512);
        gemm_kernel<true,true,false,true><<<dim3(32,64,1),blk,0,stream>>>(
            X2, dw1 + (long)l*2048*512, db1 + l*2048, nullptr, FH,
            4096,2048,512, 512,512,2048, 1,0,0,0,0,0,0);
        gemm_kernel<true,false,true,true><<<dim3(8,64,1),blk,0,stream>>>(
            FH, dw2 + (long)l*512*2048, db2 + l*512, X, X,
            4096,512,2048, 2048,2048,512, 1,0,0,0,0,0,0);
    }
    ln_kernel<<<4096,blk,0,stream>>>(X, X2, dng, dnb);

    // tied output projection: logits = dec_out . emb^T  -> f32 d_out
    gemm_kernel<true,false,false,false><<<dim3(500,64,1),blk,0,stream>>>(
        X2, emb, nullptr, nullptr, (float*)d_out, 4096,32000,512, 512,512,32000,
        1,0,0,0,0,0,0);
}